// Round 3
// baseline (237.223 us; speedup 1.0000x reference)
//
#include <hip/hip_runtime.h>
#include <hip/hip_bf16.h>
#include <float.h>

#define DEVI __device__ __forceinline__
#define AS1c(p) ((const __attribute__((address_space(1))) void*)(p))
#define AS3p(p) ((__attribute__((address_space(3))) void*)(p))

namespace {

constexpr int NB   = 8;     // batch
constexpr int CD   = 256;   // dense channels
constexpr int CS   = 512;   // sparse channels
constexpr int MM   = 4096;  // dense points
constexpr int SS   = 1024;  // sparse points
constexpr int NN   = 4096;  // pcd points
constexpr int KTOT = 768;   // CD + CS
constexpr int OC   = 256;   // output channels
constexpr float KEPS  = 1e-8f;
constexpr float BNEPS = 1e-5f;
constexpr float SLOPE = 0.2f;

// workspace layout (bytes) — total ~68.3 MB
constexpr size_t OFF_SPT  = 0;                           // float [NB][SS][CS]
constexpr size_t SZ_SPT   = (size_t)NB * SS * CS * 4;    // 16,777,216
constexpr size_t OFF_WBF  = OFF_SPT + SZ_SPT;            // bf16  [OC][KTOT]
constexpr size_t SZ_WBF   = (size_t)OC * KTOT * 2;       // 393,216
constexpr size_t OFF_X    = OFF_WBF + SZ_WBF;            // bf16  [NB*MM][KTOT]
constexpr size_t SZ_X     = (size_t)NB * MM * KTOT * 2;  // 50,331,648
constexpr size_t OFF_SSUM = OFF_X + SZ_X;                // float [2*OC]

typedef __attribute__((ext_vector_type(8))) short s16x8;
typedef __attribute__((ext_vector_type(4))) float f32x4;

// float -> bf16 (RNE), returned as raw short
DEVI short f2bf(float f) {
  union { float f; unsigned u; } c; c.f = f;
  unsigned r = c.u + 0x7fffu + ((c.u >> 16) & 1u);
  return (short)(r >> 16);
}

// ------------------------------------------- conv_w -> bf16, + zero stats acc
__global__ void k_wcast(const float* __restrict__ w, short* __restrict__ wbf,
                        float* __restrict__ ssum) {
  int i = blockIdx.x * 256 + threadIdx.x;   // grid covers OC*KTOT exactly
  if (blockIdx.x < 2) ssum[blockIdx.x * 256 + threadIdx.x] = 0.f;
  wbf[i] = f2bf(w[i]);
}

// ------------------------------------------- sparse_data [b][c][s] -> spt [b][s][c]
__global__ void k_transpose(const float* __restrict__ sp, float* __restrict__ spt) {
  __shared__ float t[32][33];
  int blk = blockIdx.x;                 // 8 * 16 * 32 = 4096 blocks
  int st = blk & 31;
  int ct = (blk >> 5) & 15;
  int b  = blk >> 9;
  int tx = threadIdx.x & 31, ty = threadIdx.x >> 5;   // 32 x 8
  int c0 = ct * 32, s0 = st * 32;
#pragma unroll
  for (int r = 0; r < 32; r += 8)
    t[ty + r][tx] = sp[((size_t)(b * CS + c0 + ty + r)) * SS + s0 + tx];
  __syncthreads();
#pragma unroll
  for (int r = 0; r < 32; r += 8)
    spt[((size_t)(b * SS + s0 + ty + r)) * CS + c0 + tx] = t[tx][ty + r];
}

// ---------------------------------------------------------------- KNN + prep
// One block per (b, 64-m tile). Phase 1: top-3 KNN (lane-per-point, LDS merge,
// results stay in LDS). Phase 2: dense transpose+cast -> X[:, 0:256].
// Phase 3: weighted 3-gather interp from spt -> X[:, 256:768].
__global__ __launch_bounds__(256) void k_knn_prep(
    const int* __restrict__ didx, const int* __restrict__ sidx,
    const float* __restrict__ pcd, const float* __restrict__ dense,
    const float* __restrict__ spt, short* __restrict__ X,
    float* __restrict__ outIdxF) {
  __shared__ union {
    struct {
      float4 sxyz[SS];                 // 16 KB candidate coords
      float  pd[4][64][3];             // partial top-3 dists
      int    pi[4][64][3];             // partial top-3 idxs
    } k;
    float tile[64][65];                // dense transpose tile (16.6 KB)
  } u;
  __shared__ int   li[192];            // final top-3 idx per m
  __shared__ float lw[192];            // final weights per m

  int blk = blockIdx.x;                // 8 * 64 = 512 blocks
  int b   = blk >> 6;
  int m0  = (blk & 63) << 6;
  int tid = threadIdx.x;
  const float* pb = pcd + (size_t)b * 3 * NN;

  for (int s = tid; s < SS; s += 256) {
    int si = sidx[b * SS + s];
    u.k.sxyz[s] = make_float4(pb[si], pb[NN + si], pb[2 * NN + si], 0.f);
  }
  int p = tid & 63, chunk = tid >> 6;
  int m = m0 + p;
  int di = didx[b * MM + m];
  float px = pb[di], py = pb[NN + di], pz = pb[2 * NN + di];
  if (chunk == 0) outIdxF[b * MM + m] = (float)di;   // output 1
  __syncthreads();

  {
    float d0 = FLT_MAX, d1 = FLT_MAX, d2 = FLT_MAX;
    int   i0 = 0, i1 = 0, i2 = 0;
    int s0c = chunk << 8;
#pragma unroll 4
    for (int t = 0; t < 256; ++t) {
      int s = s0c + t;
      float4 c = u.k.sxyz[s];
      float dx = c.x - px, dy = c.y - py, dz = c.z - pz;
      float d  = dx * dx + dy * dy + dz * dz;
      bool lt0 = d < d0, lt1 = d < d1, lt2 = d < d2;
      d2 = lt1 ? d1 : (lt2 ? d : d2);  i2 = lt1 ? i1 : (lt2 ? s : i2);
      d1 = lt0 ? d0 : (lt1 ? d : d1);  i1 = lt0 ? i0 : (lt1 ? s : i1);
      d0 = lt0 ? d  : d0;              i0 = lt0 ? s : i0;
    }
    u.k.pd[chunk][p][0] = d0; u.k.pd[chunk][p][1] = d1; u.k.pd[chunk][p][2] = d2;
    u.k.pi[chunk][p][0] = i0; u.k.pi[chunk][p][1] = i1; u.k.pi[chunk][p][2] = i2;
  }
  __syncthreads();

  if (tid < 64) {
    float e0 = FLT_MAX, e1 = FLT_MAX, e2 = FLT_MAX;
    int   j0 = 0, j1 = 0, j2 = 0;
#pragma unroll
    for (int c = 0; c < 4; ++c)
#pragma unroll
      for (int r = 0; r < 3; ++r) {
        float d = u.k.pd[c][p][r]; int s = u.k.pi[c][p][r];
        bool lt0 = d < e0, lt1 = d < e1, lt2 = d < e2;
        e2 = lt1 ? e1 : (lt2 ? d : e2);  j2 = lt1 ? j1 : (lt2 ? s : j2);
        e1 = lt0 ? e0 : (lt1 ? d : e1);  j1 = lt0 ? j0 : (lt1 ? s : j1);
        e0 = lt0 ? d  : e0;              j0 = lt0 ? s : j0;
      }
    float w0 = 1.f / (e0 + KEPS), w1 = 1.f / (e1 + KEPS), w2 = 1.f / (e2 + KEPS);
    float inv = 1.f / (w0 + w1 + w2);
    li[p * 3] = j0; li[p * 3 + 1] = j1; li[p * 3 + 2] = j2;
    lw[p * 3] = w0 * inv; lw[p * 3 + 1] = w1 * inv; lw[p * 3 + 2] = w2 * inv;
  }

  // ---- phase 2: dense [b][c][m] -> X[b*M+m][0:256] bf16 (LDS-tiled transpose)
  int tx = tid & 63, ty = tid >> 6;    // 64 x 4
  for (int ct = 0; ct < 4; ++ct) {
    __syncthreads();                   // first iter: protects union transition
#pragma unroll
    for (int r = 0; r < 16; ++r)
      u.tile[ty * 16 + r][tx] =
          dense[((size_t)b * CD + ct * 64 + ty * 16 + r) * MM + m0 + tx];
    __syncthreads();
#pragma unroll
    for (int r = 0; r < 2; ++r) {
      int lin = r * 256 + tid;         // 512 chunks of 16B
      int ml = lin >> 3, cq = lin & 7;
      short tmp[8];
#pragma unroll
      for (int uu = 0; uu < 8; ++uu) tmp[uu] = f2bf(u.tile[cq * 8 + uu][ml]);
      *(uint4*)(&X[((size_t)b * MM + m0 + ml) * KTOT + ct * 64 + cq * 8]) =
          *(const uint4*)tmp;
    }
  }

  // ---- phase 3: interp -> X[b*M+m][256:768] bf16
#pragma unroll 2
  for (int r = 0; r < 32; ++r) {
    int lin = r * 256 + tid;           // 8192 = 64 m x 128 float4-chunks
    int ml = lin >> 7, c4 = lin & 127;
    int b3 = ml * 3;
    float w0 = lw[b3], w1 = lw[b3 + 1], w2 = lw[b3 + 2];
    const float4 v0 = *(const float4*)(spt + ((size_t)b * SS + li[b3])     * CS + c4 * 4);
    const float4 v1 = *(const float4*)(spt + ((size_t)b * SS + li[b3 + 1]) * CS + c4 * 4);
    const float4 v2 = *(const float4*)(spt + ((size_t)b * SS + li[b3 + 2]) * CS + c4 * 4);
    short t2[4];
    t2[0] = f2bf(w0 * v0.x + w1 * v1.x + w2 * v2.x);
    t2[1] = f2bf(w0 * v0.y + w1 * v1.y + w2 * v2.y);
    t2[2] = f2bf(w0 * v0.z + w1 * v1.z + w2 * v2.z);
    t2[3] = f2bf(w0 * v0.w + w1 * v1.w + w2 * v2.w);
    *(uint2*)(&X[((size_t)b * MM + m0 + ml) * KTOT + CD + c4 * 4]) = *(const uint2*)t2;
  }
}

// ---------------------------------------------------------------- bf16 GEMM
// y[b,o,m] = sum_k W[o,k] * X[b*M+m][k] — both operands K-contiguous.
// 128o x 128m tile, BK=32, global_load_lds(16B) staging into unpadded 64B rows
// with row-rotation swizzle: chunk kq of row r stored at position (kq + r/2)&3.
// BN batch stats fused into epilogue via atomics.
__global__ __launch_bounds__(256) void k_gemm(
    const short* __restrict__ wbf, const short* __restrict__ X,
    float* __restrict__ y, float* __restrict__ ssum) {
  __shared__ short Al[4096];   // 128 rows x 32 k (64 B rows)
  __shared__ short Xl[4096];

  int blk = blockIdx.x;        // 512: ot = blk&1 (adjacent blocks share X tile)
  int ot = blk & 1, mt = blk >> 1;
  int o0 = ot << 7;
  int bm0 = mt << 7;           // flattened b*M + m (tile never crosses batch)
  int tid = threadIdx.x;
  int wv = tid >> 6, lane = tid & 63;
  int lo = lane & 15, quad = lane >> 4;
  int wo = (wv >> 1) << 6, wm = (wv & 1) << 6;

  // staging map: 512 16B-slots per buffer; slot q = (row, pos); source chunk
  // kq = (pos - row/2)&3. Wave wv stages slots [wv*64, wv*64+64) and +256.
  int qa0 = wv * 64 + lane;
  int qa1 = qa0 + 256;
  int r0 = qa0 >> 2, k0q = ((qa0 & 3) - (r0 >> 1)) & 3;
  int r1 = qa1 >> 2, k1q = ((qa1 & 3) - (r1 >> 1)) & 3;
  const short* pa0 = wbf + (size_t)(o0 + r0) * KTOT + k0q * 8;
  const short* pa1 = wbf + (size_t)(o0 + r1) * KTOT + k1q * 8;
  const short* px0 = X + (size_t)(bm0 + r0) * KTOT + k0q * 8;
  const short* px1 = X + (size_t)(bm0 + r1) * KTOT + k1q * 8;
  short* lA0 = &Al[wv * 512];
  short* lA1 = &Al[wv * 512 + 2048];
  short* lX0 = &Xl[wv * 512];
  short* lX1 = &Xl[wv * 512 + 2048];

  f32x4 acc[4][4] = {};

  for (int kk = 0; kk < KTOT; kk += 32) {
    __syncthreads();
    __builtin_amdgcn_global_load_lds(AS1c(pa0 + kk), AS3p(lA0), 16, 0, 0);
    __builtin_amdgcn_global_load_lds(AS1c(pa1 + kk), AS3p(lA1), 16, 0, 0);
    __builtin_amdgcn_global_load_lds(AS1c(px0 + kk), AS3p(lX0), 16, 0, 0);
    __builtin_amdgcn_global_load_lds(AS1c(px1 + kk), AS3p(lX1), 16, 0, 0);
    __syncthreads();
    s16x8 af[4], bx[4];
#pragma unroll
    for (int i = 0; i < 4; ++i) {
      int row = wo + i * 16 + lo;
      af[i] = *(const s16x8*)(&Al[row * 32 + (((quad + (row >> 1)) & 3) << 3)]);
    }
#pragma unroll
    for (int j = 0; j < 4; ++j) {
      int row = wm + j * 16 + lo;
      bx[j] = *(const s16x8*)(&Xl[row * 32 + (((quad + (row >> 1)) & 3) << 3)]);
    }
#pragma unroll
    for (int i = 0; i < 4; ++i)
#pragma unroll
      for (int j = 0; j < 4; ++j)
        acc[i][j] = __builtin_amdgcn_mfma_f32_16x16x32_bf16(af[i], bx[j], acc[i][j], 0, 0, 0);
  }

  // ---- epilogue: raw y (pre-BN) into d_out region 0
  int b  = bm0 >> 12;                  // M = 4096
  int mb = (bm0 & (MM - 1)) + wm;
#pragma unroll
  for (int i = 0; i < 4; ++i) {
    int oo = o0 + wo + i * 16 + quad * 4;
#pragma unroll
    for (int j = 0; j < 4; ++j) {
      int mm2 = mb + j * 16 + lo;
      float* dst = y + ((size_t)b * OC + oo) * MM + mm2;
#pragma unroll
      for (int r = 0; r < 4; ++r) dst[(size_t)r * MM] = acc[i][j][r];
    }
  }
  // ---- fused BN partial stats: per-channel sum/sumsq over this tile's 64 m
#pragma unroll
  for (int i = 0; i < 4; ++i)
#pragma unroll
    for (int r = 0; r < 4; ++r) {
      float s = 0.f, s2 = 0.f;
#pragma unroll
      for (int j = 0; j < 4; ++j) { float v = acc[i][j][r]; s += v; s2 += v * v; }
#pragma unroll
      for (int msk = 1; msk < 16; msk <<= 1) {
        s += __shfl_xor(s, msk); s2 += __shfl_xor(s2, msk);
      }
      if (lo == 0) {
        int oo = o0 + wo + i * 16 + quad * 4 + r;
        atomicAdd(&ssum[oo], s);
        atomicAdd(&ssum[OC + oo], s2);
      }
    }
}

// ---------------------------------------------------------------- BN apply + LeakyReLU
__global__ void k_norm(float* __restrict__ y, const float* __restrict__ ssum,
                       const float* __restrict__ gamma, const float* __restrict__ beta) {
  int i = blockIdx.x * 256 + threadIdx.x;   // float4 index; grid covers exactly
  int o = (i >> 10) & 255;                  // 1024 float4 per (b,o) row
  constexpr float inv = 1.f / (float)(NB * MM);
  float mn = ssum[o] * inv;
  float vr = ssum[OC + o] * inv - mn * mn;
  float a  = rsqrtf(vr + BNEPS) * gamma[o];
  float be = beta[o];
  float4 v = ((const float4*)y)[i];
  float t;
  t = (v.x - mn) * a + be; v.x = t >= 0.f ? t : SLOPE * t;
  t = (v.y - mn) * a + be; v.y = t >= 0.f ? t : SLOPE * t;
  t = (v.z - mn) * a + be; v.z = t >= 0.f ? t : SLOPE * t;
  t = (v.w - mn) * a + be; v.w = t >= 0.f ? t : SLOPE * t;
  ((float4*)y)[i] = v;
}

}  // namespace

extern "C" void kernel_launch(void* const* d_in, const int* in_sizes, int n_in,
                              void* d_out, int out_size, void* d_ws, size_t ws_size,
                              hipStream_t stream) {
  const float* dense = (const float*)d_in[0];
  const int*   didx  = (const int*)d_in[1];
  const float* sp    = (const float*)d_in[2];
  const int*   sidx  = (const int*)d_in[3];
  const float* pcd   = (const float*)d_in[4];
  const float* convw = (const float*)d_in[5];
  const float* gamma = (const float*)d_in[6];
  const float* beta  = (const float*)d_in[7];

  float* y = (float*)d_out;                       // [8][256][4096] raw -> normalized in place
  float* outIdxF = y + (size_t)NB * OC * MM;      // output 1: dense_idx as float

  char* ws = (char*)d_ws;                         // needs ~68.3 MB
  float* spt  = (float*)(ws + OFF_SPT);
  short* wbf  = (short*)(ws + OFF_WBF);
  short* X    = (short*)(ws + OFF_X);
  float* ssum = (float*)(ws + OFF_SSUM);

  k_wcast    <<<(OC * KTOT) / 256, 256, 0, stream>>>(convw, wbf, ssum);
  k_transpose<<<NB * (CS / 32) * (SS / 32), 256, 0, stream>>>(sp, spt);
  k_knn_prep <<<NB * (MM / 64), 256, 0, stream>>>(didx, sidx, pcd, dense, sp ? spt : spt, X, outIdxF);
  k_gemm     <<<NB * 2 * (MM / 128), 256, 0, stream>>>(wbf, X, y, ssum);
  k_norm     <<<(NB * OC * MM / 4) / 256, 256, 0, stream>>>(y, ssum, gamma, beta);
}

// Round 4
// 231.782 us; speedup vs baseline: 1.0235x; 1.0235x over previous
//
#include <hip/hip_runtime.h>
#include <hip/hip_bf16.h>
#include <float.h>

#define DEVI __device__ __forceinline__
#define AS1c(p) ((const __attribute__((address_space(1))) void*)(p))
#define AS3p(p) ((__attribute__((address_space(3))) void*)(p))

namespace {

constexpr int NB   = 8;     // batch
constexpr int CD   = 256;   // dense channels
constexpr int CS   = 512;   // sparse channels
constexpr int MM   = 4096;  // dense points
constexpr int SS   = 1024;  // sparse points
constexpr int NN   = 4096;  // pcd points
constexpr int KTOT = 768;   // CD + CS
constexpr int OC   = 256;   // output channels
constexpr float KEPS  = 1e-8f;
constexpr float BNEPS = 1e-5f;
constexpr float SLOPE = 0.2f;

// workspace layout (bytes) — total ~68.3 MB
constexpr size_t OFF_SPT  = 0;                           // float [NB][SS][CS]
constexpr size_t SZ_SPT   = (size_t)NB * SS * CS * 4;    // 16,777,216
constexpr size_t OFF_WBF  = OFF_SPT + SZ_SPT;            // bf16  [OC][KTOT]
constexpr size_t SZ_WBF   = (size_t)OC * KTOT * 2;       // 393,216
constexpr size_t OFF_X    = OFF_WBF + SZ_WBF;            // bf16  [NB*MM][KTOT]
constexpr size_t SZ_X     = (size_t)NB * MM * KTOT * 2;  // 50,331,648
constexpr size_t OFF_SSUM = OFF_X + SZ_X;                // float [2*OC]

typedef __attribute__((ext_vector_type(8))) short s16x8;
typedef __attribute__((ext_vector_type(4))) float f32x4;

// float -> bf16 (RNE), returned as raw short
DEVI short f2bf(float f) {
  union { float f; unsigned u; } c; c.f = f;
  unsigned r = c.u + 0x7fffu + ((c.u >> 16) & 1u);
  return (short)(r >> 16);
}

// ------------------------------------------- conv_w -> bf16, + zero stats acc
__global__ void k_wcast(const float* __restrict__ w, short* __restrict__ wbf,
                        float* __restrict__ ssum) {
  int i = blockIdx.x * 256 + threadIdx.x;   // grid covers OC*KTOT exactly
  if (blockIdx.x < 2) ssum[blockIdx.x * 256 + threadIdx.x] = 0.f;
  wbf[i] = f2bf(w[i]);
}

// ------------------------------------------- sparse_data [b][c][s] -> spt [b][s][c]
__global__ void k_transpose(const float* __restrict__ sp, float* __restrict__ spt) {
  __shared__ float t[32][33];
  int blk = blockIdx.x;                 // 8 * 16 * 32 = 4096 blocks
  int st = blk & 31;
  int ct = (blk >> 5) & 15;
  int b  = blk >> 9;
  int tx = threadIdx.x & 31, ty = threadIdx.x >> 5;   // 32 x 8
  int c0 = ct * 32, s0 = st * 32;
#pragma unroll
  for (int r = 0; r < 32; r += 8)
    t[ty + r][tx] = sp[((size_t)(b * CS + c0 + ty + r)) * SS + s0 + tx];
  __syncthreads();
#pragma unroll
  for (int r = 0; r < 32; r += 8)
    spt[((size_t)(b * SS + s0 + ty + r)) * CS + c0 + tx] = t[tx][ty + r];
}

// ---------------------------------------------------------------- KNN + prep
// One block per (b, 64-m tile), XCD-swizzled: b = blk%8 so each XCD works on
// one batch only -> its 2MB spt slice stays L2-resident for phase-3 gathers.
__global__ __launch_bounds__(256) void k_knn_prep(
    const int* __restrict__ didx, const int* __restrict__ sidx,
    const float* __restrict__ pcd, const float* __restrict__ dense,
    const float* __restrict__ spt, short* __restrict__ X,
    float* __restrict__ outIdxF) {
  __shared__ union {
    struct {
      float4 sxyz[SS];                 // 16 KB candidate coords
      float  pd[4][64][3];             // partial top-3 dists
      int    pi[4][64][3];             // partial top-3 idxs
    } k;
    float tile[64][65];                // dense transpose tile (16.6 KB)
  } u;
  __shared__ int   li[192];            // final top-3 idx per m
  __shared__ float lw[192];            // final weights per m

  int blk = blockIdx.x;                // 512 blocks
  int b   = blk & 7;                   // XCD swizzle: same-b -> same XCD
  int m0  = (blk >> 3) << 6;
  int tid = threadIdx.x;
  const float* pb = pcd + (size_t)b * 3 * NN;

  for (int s = tid; s < SS; s += 256) {
    int si = sidx[b * SS + s];
    u.k.sxyz[s] = make_float4(pb[si], pb[NN + si], pb[2 * NN + si], 0.f);
  }
  int p = tid & 63, chunk = tid >> 6;
  int m = m0 + p;
  int di = didx[b * MM + m];
  float px = pb[di], py = pb[NN + di], pz = pb[2 * NN + di];
  if (chunk == 0) outIdxF[b * MM + m] = (float)di;   // output 1
  __syncthreads();

  {
    float d0 = FLT_MAX, d1 = FLT_MAX, d2 = FLT_MAX;
    int   i0 = 0, i1 = 0, i2 = 0;
    int s0c = chunk << 8;
#pragma unroll 4
    for (int t = 0; t < 256; ++t) {
      int s = s0c + t;
      float4 c = u.k.sxyz[s];
      float dx = c.x - px, dy = c.y - py, dz = c.z - pz;
      float d  = dx * dx + dy * dy + dz * dz;
      bool lt0 = d < d0, lt1 = d < d1, lt2 = d < d2;
      d2 = lt1 ? d1 : (lt2 ? d : d2);  i2 = lt1 ? i1 : (lt2 ? s : i2);
      d1 = lt0 ? d0 : (lt1 ? d : d1);  i1 = lt0 ? i0 : (lt1 ? s : i1);
      d0 = lt0 ? d  : d0;              i0 = lt0 ? s : i0;
    }
    u.k.pd[chunk][p][0] = d0; u.k.pd[chunk][p][1] = d1; u.k.pd[chunk][p][2] = d2;
    u.k.pi[chunk][p][0] = i0; u.k.pi[chunk][p][1] = i1; u.k.pi[chunk][p][2] = i2;
  }
  __syncthreads();

  if (tid < 64) {
    float e0 = FLT_MAX, e1 = FLT_MAX, e2 = FLT_MAX;
    int   j0 = 0, j1 = 0, j2 = 0;
#pragma unroll
    for (int c = 0; c < 4; ++c)
#pragma unroll
      for (int r = 0; r < 3; ++r) {
        float d = u.k.pd[c][p][r]; int s = u.k.pi[c][p][r];
        bool lt0 = d < e0, lt1 = d < e1, lt2 = d < e2;
        e2 = lt1 ? e1 : (lt2 ? d : e2);  j2 = lt1 ? j1 : (lt2 ? s : j2);
        e1 = lt0 ? e0 : (lt1 ? d : e1);  j1 = lt0 ? j0 : (lt1 ? s : j1);
        e0 = lt0 ? d  : e0;              j0 = lt0 ? s : j0;
      }
    float w0 = 1.f / (e0 + KEPS), w1 = 1.f / (e1 + KEPS), w2 = 1.f / (e2 + KEPS);
    float inv = 1.f / (w0 + w1 + w2);
    li[p * 3] = j0; li[p * 3 + 1] = j1; li[p * 3 + 2] = j2;
    lw[p * 3] = w0 * inv; lw[p * 3 + 1] = w1 * inv; lw[p * 3 + 2] = w2 * inv;
  }

  // ---- phase 2: dense [b][c][m] -> X[b*M+m][0:256] bf16 (LDS-tiled transpose)
  int tx = tid & 63, ty = tid >> 6;    // 64 x 4
  for (int ct = 0; ct < 4; ++ct) {
    __syncthreads();                   // first iter: protects union transition
#pragma unroll
    for (int r = 0; r < 16; ++r)
      u.tile[ty * 16 + r][tx] =
          dense[((size_t)b * CD + ct * 64 + ty * 16 + r) * MM + m0 + tx];
    __syncthreads();
#pragma unroll
    for (int r = 0; r < 2; ++r) {
      int lin = r * 256 + tid;         // 512 chunks of 16B
      int ml = lin >> 3, cq = lin & 7;
      short tmp[8];
#pragma unroll
      for (int uu = 0; uu < 8; ++uu) tmp[uu] = f2bf(u.tile[cq * 8 + uu][ml]);
      *(uint4*)(&X[((size_t)b * MM + m0 + ml) * KTOT + ct * 64 + cq * 8]) =
          *(const uint4*)tmp;
    }
  }

  // ---- phase 3: interp -> X[b*M+m][256:768] bf16
#pragma unroll 2
  for (int r = 0; r < 32; ++r) {
    int lin = r * 256 + tid;           // 8192 = 64 m x 128 float4-chunks
    int ml = lin >> 7, c4 = lin & 127;
    int b3 = ml * 3;
    float w0 = lw[b3], w1 = lw[b3 + 1], w2 = lw[b3 + 2];
    const float4 v0 = *(const float4*)(spt + ((size_t)b * SS + li[b3])     * CS + c4 * 4);
    const float4 v1 = *(const float4*)(spt + ((size_t)b * SS + li[b3 + 1]) * CS + c4 * 4);
    const float4 v2 = *(const float4*)(spt + ((size_t)b * SS + li[b3 + 2]) * CS + c4 * 4);
    short t2[4];
    t2[0] = f2bf(w0 * v0.x + w1 * v1.x + w2 * v2.x);
    t2[1] = f2bf(w0 * v0.y + w1 * v1.y + w2 * v2.y);
    t2[2] = f2bf(w0 * v0.z + w1 * v1.z + w2 * v2.z);
    t2[3] = f2bf(w0 * v0.w + w1 * v1.w + w2 * v2.w);
    *(uint2*)(&X[((size_t)b * MM + m0 + ml) * KTOT + CD + c4 * 4]) = *(const uint2*)t2;
  }
}

// ---------------------------------------------------------------- bf16 GEMM
// y[b,o,m] = sum_k W[o,k] * X[b*M+m][k].  64o x 128m tiles -> 1024 blocks
// (4 blocks/CU).  Double-buffered LDS, ONE barrier per K-iter; stage k+1 loads
// are issued right after the barrier and fly across the whole compute phase,
// so the compiler's vmcnt(0)-before-barrier drains loads that are already
// ~done.  Row-rotation swizzle keeps ds_read_b128 conflict-free (R2: 0 confl).
// XCD swizzle: the 4 o-blocks sharing an X m-tile land on one XCD (L2 reuse).
__global__ __launch_bounds__(256) void k_gemm(
    const short* __restrict__ wbf, const short* __restrict__ X,
    float* __restrict__ y, float* __restrict__ ssum) {
  __shared__ short Al[2 * 2048];   //  64 rows x 32 k, double-buffered (8 KB)
  __shared__ short Xl[2 * 4096];   // 128 rows x 32 k, double-buffered (16 KB)

  int blk = blockIdx.x;            // 1024 blocks
  int x8  = blk & 7;               // XCD id
  int g   = blk >> 3;              // 0..127
  int ot  = g & 3;                 // 4 o-tiles of 64
  int mt  = (g >> 2) * 8 + x8;     // 0..255 — all 4 ot of mt share XCD x8
  int o0  = ot << 6;
  int bm0 = mt << 7;               // flattened b*M + m (128 | 4096: no crossing)
  int tid = threadIdx.x;
  int wv = tid >> 6, lane = tid & 63;
  int lo = lane & 15, quad = lane >> 4;
  int wo = (wv >> 1) << 5, wm = (wv & 1) << 6;   // wave tile: 32o x 64m

  // staging maps (rotation swizzle: source chunk kq of row r at pos (kq+r/2)&3)
  int rowA = tid >> 2, posA = tid & 3;
  int kqA  = (posA - (rowA >> 1)) & 3;
  const short* srcA  = wbf + (size_t)(o0 + rowA) * KTOT + kqA * 8;
  const short* srcX0 = X + (size_t)(bm0 + rowA) * KTOT + kqA * 8;        // rows 0..63
  const short* srcX1 = X + (size_t)(bm0 + 64 + rowA) * KTOT + kqA * 8;   // rows 64..127
  // wave-uniform LDS bases (HW adds lane*16)
  int aoff  = wv * 512;            // shorts
  int xoff0 = wv * 512;
  int xoff1 = 2048 + wv * 512;

  f32x4 acc[2][4] = {};

  // prologue: stage 0 -> buffer 0
  __builtin_amdgcn_global_load_lds(AS1c(srcA),  AS3p(&Al[aoff]),  16, 0, 0);
  __builtin_amdgcn_global_load_lds(AS1c(srcX0), AS3p(&Xl[xoff0]), 16, 0, 0);
  __builtin_amdgcn_global_load_lds(AS1c(srcX1), AS3p(&Xl[xoff1]), 16, 0, 0);

  for (int it = 0; it < KTOT / 32; ++it) {
    __syncthreads();                       // drains stage-it loads
    int kkn = (it + 1) * 32;
    int pn = (it + 1) & 1, p = it & 1;
    if (kkn < KTOT) {                      // issue stage it+1 -> other buffer
      __builtin_amdgcn_global_load_lds(AS1c(srcA + kkn),  AS3p(&Al[pn * 2048 + aoff]),  16, 0, 0);
      __builtin_amdgcn_global_load_lds(AS1c(srcX0 + kkn), AS3p(&Xl[pn * 4096 + xoff0]), 16, 0, 0);
      __builtin_amdgcn_global_load_lds(AS1c(srcX1 + kkn), AS3p(&Xl[pn * 4096 + xoff1]), 16, 0, 0);
    }
    const short* Ab = &Al[p * 2048];
    const short* Xb = &Xl[p * 4096];
    s16x8 af[2], bx[4];
#pragma unroll
    for (int i = 0; i < 2; ++i) {
      int row = wo + i * 16 + lo;
      af[i] = *(const s16x8*)(&Ab[row * 32 + (((quad + (row >> 1)) & 3) << 3)]);
    }
#pragma unroll
    for (int j = 0; j < 4; ++j) {
      int row = wm + j * 16 + lo;
      bx[j] = *(const s16x8*)(&Xb[row * 32 + (((quad + (row >> 1)) & 3) << 3)]);
    }
#pragma unroll
    for (int i = 0; i < 2; ++i)
#pragma unroll
      for (int j = 0; j < 4; ++j)
        acc[i][j] = __builtin_amdgcn_mfma_f32_16x16x32_bf16(af[i], bx[j], acc[i][j], 0, 0, 0);
  }

  // ---- epilogue: raw y (pre-BN) into d_out region 0
  int b  = bm0 >> 12;                  // M = 4096
  int mb = (bm0 & (MM - 1)) + wm;
#pragma unroll
  for (int i = 0; i < 2; ++i) {
    int oo = o0 + wo + i * 16 + quad * 4;
#pragma unroll
    for (int j = 0; j < 4; ++j) {
      int mm2 = mb + j * 16 + lo;
      float* dst = y + ((size_t)b * OC + oo) * MM + mm2;
#pragma unroll
      for (int r = 0; r < 4; ++r) dst[(size_t)r * MM] = acc[i][j][r];
    }
  }
  // ---- fused BN partial stats: per-channel sum/sumsq over this tile's 64 m
#pragma unroll
  for (int i = 0; i < 2; ++i)
#pragma unroll
    for (int r = 0; r < 4; ++r) {
      float s = 0.f, s2 = 0.f;
#pragma unroll
      for (int j = 0; j < 4; ++j) { float v = acc[i][j][r]; s += v; s2 += v * v; }
#pragma unroll
      for (int msk = 1; msk < 16; msk <<= 1) {
        s += __shfl_xor(s, msk); s2 += __shfl_xor(s2, msk);
      }
      if (lo == 0) {
        int oo = o0 + wo + i * 16 + quad * 4 + r;
        atomicAdd(&ssum[oo], s);
        atomicAdd(&ssum[OC + oo], s2);
      }
    }
}

// ---------------------------------------------------------------- BN apply + LeakyReLU
__global__ void k_norm(float* __restrict__ y, const float* __restrict__ ssum,
                       const float* __restrict__ gamma, const float* __restrict__ beta) {
  int i = blockIdx.x * 256 + threadIdx.x;   // float4 index; grid covers exactly
  int o = (i >> 10) & 255;                  // 1024 float4 per (b,o) row
  constexpr float inv = 1.f / (float)(NB * MM);
  float mn = ssum[o] * inv;
  float vr = ssum[OC + o] * inv - mn * mn;
  float a  = rsqrtf(vr + BNEPS) * gamma[o];
  float be = beta[o];
  float4 v = ((const float4*)y)[i];
  float t;
  t = (v.x - mn) * a + be; v.x = t >= 0.f ? t : SLOPE * t;
  t = (v.y - mn) * a + be; v.y = t >= 0.f ? t : SLOPE * t;
  t = (v.z - mn) * a + be; v.z = t >= 0.f ? t : SLOPE * t;
  t = (v.w - mn) * a + be; v.w = t >= 0.f ? t : SLOPE * t;
  ((float4*)y)[i] = v;
}

}  // namespace

extern "C" void kernel_launch(void* const* d_in, const int* in_sizes, int n_in,
                              void* d_out, int out_size, void* d_ws, size_t ws_size,
                              hipStream_t stream) {
  const float* dense = (const float*)d_in[0];
  const int*   didx  = (const int*)d_in[1];
  const float* sp    = (const float*)d_in[2];
  const int*   sidx  = (const int*)d_in[3];
  const float* pcd   = (const float*)d_in[4];
  const float* convw = (const float*)d_in[5];
  const float* gamma = (const float*)d_in[6];
  const float* beta  = (const float*)d_in[7];

  float* y = (float*)d_out;                       // [8][256][4096] raw -> normalized in place
  float* outIdxF = y + (size_t)NB * OC * MM;      // output 1: dense_idx as float

  char* ws = (char*)d_ws;                         // needs ~68.3 MB
  float* spt  = (float*)(ws + OFF_SPT);
  short* wbf  = (short*)(ws + OFF_WBF);
  short* X    = (short*)(ws + OFF_X);
  float* ssum = (float*)(ws + OFF_SSUM);

  k_wcast    <<<(OC * KTOT) / 256, 256, 0, stream>>>(convw, wbf, ssum);
  k_transpose<<<NB * (CS / 32) * (SS / 32), 256, 0, stream>>>(sp, spt);
  k_knn_prep <<<NB * (MM / 64), 256, 0, stream>>>(didx, sidx, pcd, dense, spt, X, outIdxF);
  k_gemm     <<<NB * (MM / 128) * 4, 256, 0, stream>>>(wbf, X, y, ssum);
  k_norm     <<<(NB * OC * MM / 4) / 256, 256, 0, stream>>>(y, ssum, gamma, beta);
}